// Round 20
// baseline (827.716 us; speedup 1.0000x reference)
//
#include <hip/hip_runtime.h>
#include <math.h>

#define BB 32
#define TT 32
#define D_INX 128
#define NSLOT 512
#define MLEN 64
#define NREAD 4
#define NHEAD 5
#define CDIM 256
#define IDIM 478
#define RHL 70
#define NT 512          // threads per block (8 waves, 2 per SIMD)

// d_ws layout (f32):
//   xp   [32][32][256]        = 1048576 B @ 0        (precomputed x@Wc_x + bc)
//   wct  [32 chunks][256][8]  =  262144 B @ XP_SZ    (Wc rows 128..383, f32 packed)
//   hkb  [32 chunks][478][8]  =  489472 B @ XP_SZ+WCT_SZ
#define XP_SZ   1048576
#define WCT_OFF XP_SZ
#define HKB_OFF (XP_SZ + 262144)

typedef short bf8 __attribute__((ext_vector_type(8)));     // 8 bf16 (4 VGPRs)
typedef float f32x4 __attribute__((ext_vector_type(4)));   // MFMA accumulator

struct SMem {
    float mem[NSLOT * MLEN];     // 131072 B — XOR-swizzled: logical f4 j of row n at slot j^(n&15)
    float w4[NSLOT * 4];         //   8192  read-head weights packed [n][4]
    float ww[NSLOT];             //   2048  write-head weights
    float mn[NSLOT];             //   2048
    float ctrl[256];             //   1024  (unused; layout keep)
    float h[CDIM];               //   1024
    float instr[480];            //   1920
    float k[NHEAD * MLEN];       //   1280
    float e[MLEN];               //    256
    float a[MLEN];               //    256
    float u[NHEAD * NSLOT];      //  10240  [0..2047] P56 r-partials [8 waves][4 heads][64]
                                 //         [2048..2303] P1 K-half scratch
};                               // 159360 B <= 163840

__device__ __forceinline__ float rlane(float v, int l) {
    return __int_as_float(__builtin_amdgcn_readlane(__float_as_int(v), l));
}

// split 8 f32 into bf16 hi frag + bf16 lo (residual) frag: a ~= hi + lo
__device__ __forceinline__ void cvt_hi_lo(const float* a, bf8* hi, bf8* lo) {
    union { unsigned u[4]; bf8 v; } H, L;
#pragma unroll
    for (int p = 0; p < 4; ++p) {
        unsigned hu;
        asm("v_cvt_pk_bf16_f32 %0, %1, %2" : "=v"(hu) : "v"(a[2 * p]), "v"(a[2 * p + 1]));
        H.u[p] = hu;
        float h0 = __uint_as_float(hu << 16);
        float h1 = __uint_as_float(hu & 0xffff0000u);
        float l0 = a[2 * p] - h0;
        float l1 = a[2 * p + 1] - h1;
        unsigned lu;
        asm("v_cvt_pk_bf16_f32 %0, %1, %2" : "=v"(lu) : "v"(l0), "v"(l1));
        L.u[p] = lu;
    }
    *hi = H.v; *lo = L.v;
}

// pack r-part of Wc (rows 128..383) and all of Hk as f32 [chunk][col][8]
__global__ void pack_kernel(const float* __restrict__ Wc, const float* __restrict__ Hk,
                            float* __restrict__ wct, float* __restrict__ hkb)
{
    int idx = blockIdx.x * 256 + threadIdx.x;
    if (idx < 256 * 256) {                       // 32 chunks x 8 rows = 256 r-rows
        int i = idx >> 8, col = idx & 255;       // i = r-row (0..255), actual row 128+i
        wct[((i >> 3) * 256 + col) * 8 + (i & 7)] = Wc[(128 + i) * 256 + col];
    }
    if (idx < 256 * 478) {
        int i = idx / 478, col = idx - i * 478;
        hkb[((i >> 3) * 478 + col) * 8 + (i & 7)] = Hk[i * 478 + col];
    }
}

// xp[bt][col] = bc[col] + sum_k x[bt][k] * Wc[k][col]   (recurrence-independent)
__global__ __launch_bounds__(256)
void xpart_kernel(const float* __restrict__ x, const float* __restrict__ Wc,
                  const float* __restrict__ bc, float* __restrict__ xp)
{
    __shared__ float xs[D_INX];
    const int bt = blockIdx.x, col = threadIdx.x;
    if (col < D_INX) xs[col] = x[(size_t)bt * D_INX + col];
    __syncthreads();
    float acc = bc[col];
#pragma unroll 8
    for (int k = 0; k < D_INX; ++k) acc += xs[k] * Wc[k * 256 + col];
    xp[(size_t)bt * CDIM + col] = acc;
}

// one GEMV1 r-part chunk (f32 weights, no unpack); cg_ MUST fold to constant
#define P1_CHUNK(cg_) do {                                                      \
    const float4 w0 = wqa[(cg_) * 512];                                         \
    const float4 w1 = wqa[(cg_) * 512 + 1];                                     \
    const int k0 = (cg_) * 8;                                                   \
    float a0 = rlane(creg[(k0 + 0) >> 6], (k0 + 0) & 63);                       \
    float a1 = rlane(creg[(k0 + 1) >> 6], (k0 + 1) & 63);                       \
    float a2 = rlane(creg[(k0 + 2) >> 6], (k0 + 2) & 63);                       \
    float a3 = rlane(creg[(k0 + 3) >> 6], (k0 + 3) & 63);                       \
    float a4 = rlane(creg[(k0 + 4) >> 6], (k0 + 4) & 63);                       \
    float a5 = rlane(creg[(k0 + 5) >> 6], (k0 + 5) & 63);                       \
    float a6 = rlane(creg[(k0 + 6) >> 6], (k0 + 6) & 63);                       \
    float a7 = rlane(creg[(k0 + 7) >> 6], (k0 + 7) & 63);                       \
    accs[(cg_) & 3] += w0.x * a0 + w0.y * a1 + w0.z * a2 + w0.w * a3            \
                     + w1.x * a4 + w1.y * a5 + w1.z * a6 + w1.w * a7;           \
} while (0)

__global__ __launch_bounds__(NT, 2)
void ntm_kernel(const float* __restrict__ xp,
                const float* __restrict__ hb,
                const float* __restrict__ wct,
                const float* __restrict__ hkb,
                float* __restrict__ out)
{
    extern __shared__ float smem_f[];
    SMem* sc = (SMem*)smem_f;

    const int b    = blockIdx.x;
    const int tid  = threadIdx.x;
    const int lane = tid & 63;
    const int wave = tid >> 6;   // 0..7

    // GEMV1 mapping: col = tid&255, K-half = tid>>8 (WAVE-uniform: waves 0-3 / 4-7)
    const int col   = tid & 255;
    const int halfw = tid >> 8;

    const float hbv = (tid < IDIM) ? hb[tid] : 0.f;

    // ---- prologue ----
    {
        float4 z4 = make_float4(0.f, 0.f, 0.f, 0.f);
        float4* m4 = (float4*)sc->mem;
        for (int i = tid; i < NSLOT * MLEN / 4; i += NT) m4[i] = z4;
        for (int i = tid; i < NSLOT * 4; i += NT) sc->w4[i] = 0.f;
        if (tid < NSLOT) sc->ww[tid] = 0.f;
        for (int i = tid; i < 2048; i += NT) sc->u[i] = 0.f;   // r partials = 0
    }
    __syncthreads();

    for (int t = 0; t < TT; ++t) {
        // ---- P1: GEMV1 r-part; r reduced INLINE from P56 wave-partials (P0 fused) ----
        {
            const float xpv = xp[(size_t)(b * TT + t) * CDIM + col];   // issued early

            float creg[4];
            {
                const int jb = halfw * 2;      // this half needs creg[jb], creg[jb+1] only
                float s0a = sc->u[jb * 64 + lane];
                float s1a = sc->u[(jb + 1) * 64 + lane];
#pragma unroll
                for (int w = 1; w < 8; ++w) {
                    s0a += sc->u[w * 256 + jb * 64 + lane];
                    s1a += sc->u[w * 256 + (jb + 1) * 64 + lane];
                }
                creg[jb] = s0a; creg[jb + 1] = s1a;
                creg[jb ^ 2] = 0.f; creg[(jb ^ 2) + 1] = 0.f;   // unused half (never readlane'd)
            }

            const float4* wqa = (const float4*)wct + col * 2;
            float accs[4] = {0.f, 0.f, 0.f, 0.f};
            if (halfw == 0) {
#pragma unroll
                for (int cc = 0; cc < 16; ++cc) P1_CHUNK(cc);
            } else {
#pragma unroll
                for (int cc = 0; cc < 16; ++cc) P1_CHUNK(16 + cc);
            }
            float s = (accs[0] + accs[1]) + (accs[2] + accs[3]);
            if (halfw == 1) sc->u[2048 + col] = s;    // scratch: disjoint from partials
            __syncthreads();                               // B1
            if (halfw == 0) {
                float z = xpv + s + sc->u[2048 + col];
                z = fminf(fmaxf(z, -15.f), 15.f);
                float ex = __expf(2.f * z);
                float hv = (ex - 1.f) / (ex + 1.f);
                sc->h[col] = hv;
                if (t == TT - 1) out[(size_t)b * CDIM + col] = hv;
            }
        }
        if (t == TT - 1) break;
        __syncthreads();                                   // B2

        // ---- P2: GEMV2 + P3 kc=0 A-prep fused (prep hides under L2 weight stalls) ----
        bf8 pahi[4], palo[4];
        float pnsq[4];
        {
            float hreg[4];                                 // loaded by ALL threads (full-wave defined)
#pragma unroll
            for (int j = 0; j < 4; ++j) hreg[j] = sc->h[64 * j + lane];
            if (tid < IDIM) {
                const float4* wq2a = (const float4*)hkb + tid * 2;
                float accs[4] = {0.f, 0.f, 0.f, 0.f};
#pragma unroll
                for (int c = 0; c < 32; ++c) {
                    const float4 w0 = wq2a[c * 956];
                    const float4 w1 = wq2a[c * 956 + 1];
                    const int k0 = c * 8;
                    float a0 = rlane(hreg[(k0 + 0) >> 6], (k0 + 0) & 63);
                    float a1 = rlane(hreg[(k0 + 1) >> 6], (k0 + 1) & 63);
                    float a2 = rlane(hreg[(k0 + 2) >> 6], (k0 + 2) & 63);
                    float a3 = rlane(hreg[(k0 + 3) >> 6], (k0 + 3) & 63);
                    float a4 = rlane(hreg[(k0 + 4) >> 6], (k0 + 4) & 63);
                    float a5 = rlane(hreg[(k0 + 5) >> 6], (k0 + 5) & 63);
                    float a6 = rlane(hreg[(k0 + 6) >> 6], (k0 + 6) & 63);
                    float a7 = rlane(hreg[(k0 + 7) >> 6], (k0 + 7) & 63);
                    accs[c & 3] += w0.x * a0 + w0.y * a1 + w0.z * a2 + w0.w * a3
                                 + w1.x * a4 + w1.y * a5 + w1.z * a6 + w1.w * a7;
                }
                float acc = hbv + (accs[0] + accs[1]) + (accs[2] + accs[3]);
                sc->instr[tid] = acc;
                if (tid < 350) {
                    int hh = (tid * 937) >> 16;     // tid/70
                    int m = tid - hh * RHL;
                    if (m < MLEN) sc->k[hh * MLEN + m] = acc;
                } else if (tid < 414) {
                    sc->e[tid - 350] = acc;
                } else {
                    sc->a[tid - 414] = acc;
                }
            }
            // P3 A-prep (kc=0): depends only on Mem (stable since B6) — overlap work
            {
                const int q = lane >> 4, r15 = lane & 15;
#pragma unroll
                for (int tt2 = 0; tt2 < 4; ++tt2) {
                    const int n = wave * 64 + tt2 * 16 + r15;
                    const int nx = n & 15;
                    const float4* m4p = (const float4*)sc->mem + n * 16;
                    const int j0 = q * 2;
                    float4 av0 = m4p[j0 ^ nx];
                    float4 av1 = m4p[(j0 + 1) ^ nx];
                    float aa[8];
                    aa[0] = av0.x; aa[1] = av0.y; aa[2] = av0.z; aa[3] = av0.w;
                    aa[4] = av1.x; aa[5] = av1.y; aa[6] = av1.z; aa[7] = av1.w;
                    float ns = 0.f;
#pragma unroll
                    for (int i = 0; i < 8; ++i) ns += aa[i] * aa[i];
                    pnsq[tt2] = ns;
                    cvt_hi_lo(aa, &pahi[tt2], &palo[tt2]);
                }
            }
        }
        __syncthreads();                                   // B3

        // ---- P3: sim dots via MFMA (kc=0 from prepped frags; kc=1 loaded here) ----
        {
            const int q   = lane >> 4;    // k-group 0..3
            const int r15 = lane & 15;    // A row-within-tile / B head col

            bf8 bhi[2], blo[2];
#pragma unroll
            for (int kc = 0; kc < 2; ++kc) {
                float kb[8];
                if (r15 < NHEAD) {
                    const float4* k4 = (const float4*)(sc->k + r15 * MLEN + kc * 32 + q * 8);
                    float4 kv0 = k4[0], kv1 = k4[1];
                    kb[0] = kv0.x; kb[1] = kv0.y; kb[2] = kv0.z; kb[3] = kv0.w;
                    kb[4] = kv1.x; kb[5] = kv1.y; kb[6] = kv1.z; kb[7] = kv1.w;
                } else {
#pragma unroll
                    for (int i = 0; i < 8; ++i) kb[i] = 0.f;
                }
                cvt_hi_lo(kb, &bhi[kc], &blo[kc]);
            }

#pragma unroll
            for (int tt2 = 0; tt2 < 4; ++tt2) {
                const int tbase = wave * 64 + tt2 * 16;
                const int n = tbase + r15;
                const int nx = n & 15;
                const float4* m4 = (const float4*)sc->mem + n * 16;
                f32x4 acc = {0.f, 0.f, 0.f, 0.f};
                // kc=0: prepped fragments
                acc = __builtin_amdgcn_mfma_f32_16x16x32_bf16(pahi[tt2], bhi[0], acc, 0, 0, 0);
                acc = __builtin_amdgcn_mfma_f32_16x16x32_bf16(pahi[tt2], blo[0], acc, 0, 0, 0);
                acc = __builtin_amdgcn_mfma_f32_16x16x32_bf16(palo[tt2], bhi[0], acc, 0, 0, 0);
                // kc=1: load + cvt now
                const int j0 = 8 + q * 2;
                float4 av0 = m4[j0 ^ nx];
                float4 av1 = m4[(j0 + 1) ^ nx];
                float aa[8];
                aa[0] = av0.x; aa[1] = av0.y; aa[2] = av0.z; aa[3] = av0.w;
                aa[4] = av1.x; aa[5] = av1.y; aa[6] = av1.z; aa[7] = av1.w;
                float nsq = pnsq[tt2];
#pragma unroll
                for (int i = 0; i < 8; ++i) nsq += aa[i] * aa[i];
                bf8 ahi, alo;
                cvt_hi_lo(aa, &ahi, &alo);
                acc = __builtin_amdgcn_mfma_f32_16x16x32_bf16(ahi, bhi[1], acc, 0, 0, 0);
                acc = __builtin_amdgcn_mfma_f32_16x16x32_bf16(ahi, blo[1], acc, 0, 0, 0);
                acc = __builtin_amdgcn_mfma_f32_16x16x32_bf16(alo, bhi[1], acc, 0, 0, 0);
                nsq += __shfl_xor(nsq, 16);
                nsq += __shfl_xor(nsq, 32);
                if (q == 0) sc->mn[n] = sqrtf(nsq);
                if (r15 < NHEAD) {
                    float4 st;
                    st.x = acc[0]; st.y = acc[1]; st.z = acc[2]; st.w = acc[3];
                    *(float4*)&sc->u[r15 * NSLOT + tbase + q * 4] = st;
                }
            }
        }
        __syncthreads();                                   // B4

        // ---- P4: addressing, one wave per head (heads 0-3 packed w4, head 4 ww) ----
        if (wave < NHEAD) {
            const int h = wave;
            const float* ins = sc->instr + h * RHL;
            float kv = ins[lane];
            float sq = kv * kv;
#pragma unroll
            for (int off = 32; off; off >>= 1) sq += __shfl_xor(sq, off);
            float kn = sqrtf(sq);
            float beta = __expf(ins[64]);
            float g = 1.f / (1.f + __expf(-ins[65]));
            float v0 = ins[66], v1 = ins[67], v2 = ins[68];
            float mx3 = fmaxf(v0, fmaxf(v1, v2));
            float e0 = __expf(v0 - mx3), e1 = __expf(v1 - mx3), e2 = __expf(v2 - mx3);
            float inv3 = 1.f / (e0 + e1 + e2);
            float s0 = e0 * inv3, s1 = e1 * inv3, s2 = e2 * inv3;
            float tv = ins[69];
            float tp = fmaxf(tv, 0.f) + log1pf(__expf(-fabsf(tv))) + 1.f;

            float uu[8];
#pragma unroll
            for (int j = 0; j < 8; ++j) {
                int slot = j * 64 + lane;
                float d = sc->u[h * NSLOT + slot];
                uu[j] = beta * d / (kn * sc->mn[slot] + 1e-8f);
            }
            float m = uu[0];
#pragma unroll
            for (int j = 1; j < 8; ++j) m = fmaxf(m, uu[j]);
#pragma unroll
            for (int off = 32; off; off >>= 1) m = fmaxf(m, __shfl_xor(m, off));
            float ev[8]; float Z = 0.f;
#pragma unroll
            for (int j = 0; j < 8; ++j) { ev[j] = __expf(uu[j] - m); Z += ev[j]; }
#pragma unroll
            for (int off = 32; off; off >>= 1) Z += __shfl_xor(Z, off);
            float invZ = 1.f / Z;
            float wg[8];
#pragma unroll
            for (int j = 0; j < 8; ++j) {
                int slot = j * 64 + lane;
                float oldw = (h < 4) ? sc->w4[slot * 4 + h] : sc->ww[slot];
                wg[j] = g * ev[j] * invZ + (1.f - g) * oldw;
            }
            // ring shift: fold the wrap-fix into the shuffled SOURCE value
            int lm = (lane + 63) & 63, lp = (lane + 1) & 63;
            float rm[8], rp[8];
#pragma unroll
            for (int j = 0; j < 8; ++j) {
                float sm = (lane == 63) ? wg[(j + 7) & 7] : wg[j];
                float sp = (lane == 0)  ? wg[(j + 1) & 7] : wg[j];
                rm[j] = __shfl(sm, lm);
                rp[j] = __shfl(sp, lp);
            }
            float wt[8]; float S = 0.f;
#pragma unroll
            for (int j = 0; j < 8; ++j) {
                float wsh = s0 * rp[j] + s1 * wg[j] + s2 * rm[j];
                wt[j] = __builtin_amdgcn_exp2f(tp * __builtin_amdgcn_logf(wsh));
                S += wt[j];
            }
#pragma unroll
            for (int off = 32; off; off >>= 1) S += __shfl_xor(S, off);
            float invS = 1.f / (S + 1e-8f);
#pragma unroll
            for (int j = 0; j < 8; ++j) {
                int slot = j * 64 + lane;
                float wnew = wt[j] * invS;
                if (h < 4) sc->w4[slot * 4 + h] = wnew;
                else       sc->ww[slot] = wnew;
            }
        }
        __syncthreads();                                   // B5

        // ---- P56: erase/add update (unchanged) + MFMA read-accumulate -> wave partials ----
        {
            const int rg = lane >> 4, j = lane & 15, base = wave * 64;
            const float4 ev = ((const float4*)sc->e)[j];
            const float4 av = ((const float4*)sc->a)[j];
            float4* m4 = (float4*)sc->mem;
#pragma unroll
            for (int i = 0; i < 16; ++i) {
                const int n = base + 4 * i + rg;
                const int idx = n * 16 + (j ^ (n & 15));
                float4 mv = m4[idx];
                const float wv = sc->ww[n];
                mv.x = mv.x * (1.f - wv * ev.x) + wv * av.x;
                mv.y = mv.y * (1.f - wv * ev.y) + wv * av.y;
                mv.z = mv.z * (1.f - wv * ev.z) + wv * av.z;
                mv.w = mv.w * (1.f - wv * ev.w) + wv * av.w;
                m4[idx] = mv;
            }
            // MFMA: r_partial[head 0..3][m 0..63] = w4^T (4x64) @ Mem'(64x64), this wave's rows.
            const int q = rg, r15 = j;    // aliases: q=lane>>4, r15=lane&15
            bf8 ahi[2], alo[2];
#pragma unroll
            for (int kc = 0; kc < 2; ++kc) {
                float ab[8];
#pragma unroll
                for (int i = 0; i < 8; ++i) {
                    const int n2 = base + kc * 32 + q * 8 + i;
                    ab[i] = (r15 < 4) ? sc->w4[n2 * 4 + r15] : 0.f;
                }
                cvt_hi_lo(ab, &ahi[kc], &alo[kc]);
            }
#pragma unroll
            for (int tt2 = 0; tt2 < 4; ++tt2) {
                f32x4 acc = {0.f, 0.f, 0.f, 0.f};
#pragma unroll
                for (int kc = 0; kc < 2; ++kc) {
                    float bb[8];
#pragma unroll
                    for (int i = 0; i < 8; ++i) {
                        const int n2 = base + kc * 32 + q * 8 + i;
                        const int cc = tt2 * 16 + r15;
                        bb[i] = sc->mem[n2 * 64 + (((cc >> 2) ^ (n2 & 15)) << 2) + (cc & 3)];
                    }
                    bf8 bhi, blo;
                    cvt_hi_lo(bb, &bhi, &blo);
                    acc = __builtin_amdgcn_mfma_f32_16x16x32_bf16(ahi[kc], bhi, acc, 0, 0, 0);
                    acc = __builtin_amdgcn_mfma_f32_16x16x32_bf16(ahi[kc], blo, acc, 0, 0, 0);
                    acc = __builtin_amdgcn_mfma_f32_16x16x32_bf16(alo[kc], bhi, acc, 0, 0, 0);
                }
                if (q == 0) {                 // C rows 0..3 = heads 0..3 live in q==0 lanes
#pragma unroll
                    for (int reg = 0; reg < 4; ++reg)
                        sc->u[wave * 256 + reg * 64 + tt2 * 16 + r15] = acc[reg];
                }
            }
        }
        __syncthreads();                                   // B6
    }
}

extern "C" void kernel_launch(void* const* d_in, const int* in_sizes, int n_in,
                              void* d_out, int out_size, void* d_ws, size_t ws_size,
                              hipStream_t stream) {
    const float* x  = (const float*)d_in[0];
    const float* Wc = (const float*)d_in[1];
    const float* bc = (const float*)d_in[2];
    const float* Hk = (const float*)d_in[3];
    const float* hb = (const float*)d_in[4];
    float* out = (float*)d_out;

    float* xp  = (float*)d_ws;
    float* wct = (float*)((char*)d_ws + WCT_OFF);
    float* hkb = (float*)((char*)d_ws + HKB_OFF);

    static_assert(sizeof(SMem) <= 163840, "LDS overflow");
    (void)hipFuncSetAttribute((const void*)ntm_kernel,
                              hipFuncAttributeMaxDynamicSharedMemorySize,
                              (int)sizeof(SMem));

    hipLaunchKernelGGL(pack_kernel, dim3(478), dim3(256), 0, stream, Wc, Hk, wct, hkb);
    hipLaunchKernelGGL(xpart_kernel, dim3(BB * TT), dim3(256), 0, stream, x, Wc, bc, xp);
    hipLaunchKernelGGL(ntm_kernel, dim3(BB), dim3(NT), sizeof(SMem), stream,
                       xp, hb, wct, hkb, out);
}

// Round 21
// 740.473 us; speedup vs baseline: 1.1178x; 1.1178x over previous
//
#include <hip/hip_runtime.h>
#include <math.h>

#define BB 32
#define TT 32
#define D_INX 128
#define NSLOT 512
#define MLEN 64
#define NREAD 4
#define NHEAD 5
#define CDIM 256
#define IDIM 478
#define RHL 70
#define NT 512          // threads per block (8 waves, 2 per SIMD)

// d_ws layout (f32):
//   xp   [32][32][256]        = 1048576 B @ 0        (precomputed x@Wc_x + bc)
//   wct  [32 chunks][256][8]  =  262144 B @ XP_SZ    (Wc rows 128..383, f32 packed)
//   hkb  [32 chunks][478][8]  =  489472 B @ XP_SZ+WCT_SZ
#define XP_SZ   1048576
#define WCT_OFF XP_SZ
#define HKB_OFF (XP_SZ + 262144)

typedef short bf8 __attribute__((ext_vector_type(8)));     // 8 bf16 (4 VGPRs)
typedef float f32x4 __attribute__((ext_vector_type(4)));   // MFMA accumulator

struct SMem {
    float mem[NSLOT * MLEN];     // 131072 B — XOR-swizzled: logical f4 j of row n at slot j^(n&15)
    float w4[NSLOT * 4];         //   8192  read-head weights packed [n][4]
    float ww[NSLOT];             //   2048  write-head weights
    float mn[NSLOT];             //   2048
    float ctrl[256];             //   1024  reduced r [4 heads][64]
    float h[CDIM];               //   1024
    float instr[480];            //   1920
    float k[NHEAD * MLEN];       //   1280
    float e[MLEN];               //    256
    float a[MLEN];               //    256
    float u[NHEAD * NSLOT];      //  10240  sim dots | P56 r-partials [8 waves][256] | P1 scratch
};                               // 159360 B <= 163840

__device__ __forceinline__ float rlane(float v, int l) {
    return __int_as_float(__builtin_amdgcn_readlane(__float_as_int(v), l));
}

// split 8 f32 into bf16 hi frag + bf16 lo (residual) frag: a ~= hi + lo
__device__ __forceinline__ void cvt_hi_lo(const float* a, bf8* hi, bf8* lo) {
    union { unsigned u[4]; bf8 v; } H, L;
#pragma unroll
    for (int p = 0; p < 4; ++p) {
        unsigned hu;
        asm("v_cvt_pk_bf16_f32 %0, %1, %2" : "=v"(hu) : "v"(a[2 * p]), "v"(a[2 * p + 1]));
        H.u[p] = hu;
        float h0 = __uint_as_float(hu << 16);
        float h1 = __uint_as_float(hu & 0xffff0000u);
        float l0 = a[2 * p] - h0;
        float l1 = a[2 * p + 1] - h1;
        unsigned lu;
        asm("v_cvt_pk_bf16_f32 %0, %1, %2" : "=v"(lu) : "v"(l0), "v"(l1));
        L.u[p] = lu;
    }
    *hi = H.v; *lo = L.v;
}

// pack r-part of Wc (rows 128..383) and all of Hk as f32 [chunk][col][8]
__global__ void pack_kernel(const float* __restrict__ Wc, const float* __restrict__ Hk,
                            float* __restrict__ wct, float* __restrict__ hkb)
{
    int idx = blockIdx.x * 256 + threadIdx.x;
    if (idx < 256 * 256) {                       // 32 chunks x 8 rows = 256 r-rows
        int i = idx >> 8, col = idx & 255;       // i = r-row (0..255), actual row 128+i
        wct[((i >> 3) * 256 + col) * 8 + (i & 7)] = Wc[(128 + i) * 256 + col];
    }
    if (idx < 256 * 478) {
        int i = idx / 478, col = idx - i * 478;
        hkb[((i >> 3) * 478 + col) * 8 + (i & 7)] = Hk[i * 478 + col];
    }
}

// xp[bt][col] = bc[col] + sum_k x[bt][k] * Wc[k][col]   (recurrence-independent)
__global__ __launch_bounds__(256)
void xpart_kernel(const float* __restrict__ x, const float* __restrict__ Wc,
                  const float* __restrict__ bc, float* __restrict__ xp)
{
    __shared__ float xs[D_INX];
    const int bt = blockIdx.x, col = threadIdx.x;
    if (col < D_INX) xs[col] = x[(size_t)bt * D_INX + col];
    __syncthreads();
    float acc = bc[col];
#pragma unroll 8
    for (int k = 0; k < D_INX; ++k) acc += xs[k] * Wc[k * 256 + col];
    xp[(size_t)bt * CDIM + col] = acc;
}

// one GEMV1 r-part chunk (f32 weights, no unpack); cg_ MUST fold to constant
#define P1_CHUNK(cg_) do {                                                      \
    const float4 w0 = wqa[(cg_) * 512];                                         \
    const float4 w1 = wqa[(cg_) * 512 + 1];                                     \
    const int k0 = (cg_) * 8;                                                   \
    float a0 = rlane(creg[(k0 + 0) >> 6], (k0 + 0) & 63);                       \
    float a1 = rlane(creg[(k0 + 1) >> 6], (k0 + 1) & 63);                       \
    float a2 = rlane(creg[(k0 + 2) >> 6], (k0 + 2) & 63);                       \
    float a3 = rlane(creg[(k0 + 3) >> 6], (k0 + 3) & 63);                       \
    float a4 = rlane(creg[(k0 + 4) >> 6], (k0 + 4) & 63);                       \
    float a5 = rlane(creg[(k0 + 5) >> 6], (k0 + 5) & 63);                       \
    float a6 = rlane(creg[(k0 + 6) >> 6], (k0 + 6) & 63);                       \
    float a7 = rlane(creg[(k0 + 7) >> 6], (k0 + 7) & 63);                       \
    accs[(cg_) & 3] += w0.x * a0 + w0.y * a1 + w0.z * a2 + w0.w * a3            \
                     + w1.x * a4 + w1.y * a5 + w1.z * a6 + w1.w * a7;           \
} while (0)

__global__ __launch_bounds__(NT, 2)
void ntm_kernel(const float* __restrict__ xp,
                const float* __restrict__ hb,
                const float* __restrict__ wct,
                const float* __restrict__ hkb,
                float* __restrict__ out)
{
    extern __shared__ float smem_f[];
    SMem* sc = (SMem*)smem_f;

    const int b    = blockIdx.x;
    const int tid  = threadIdx.x;
    const int lane = tid & 63;
    const int wave = tid >> 6;   // 0..7

    // GEMV1 mapping: col = tid&255, K-half = tid>>8 (WAVE-uniform: waves 0-3 / 4-7)
    const int col   = tid & 255;
    const int halfw = tid >> 8;

    const float hbv = (tid < IDIM) ? hb[tid] : 0.f;

    // ---- prologue ----
    {
        float4 z4 = make_float4(0.f, 0.f, 0.f, 0.f);
        float4* m4 = (float4*)sc->mem;
        for (int i = tid; i < NSLOT * MLEN / 4; i += NT) m4[i] = z4;
        for (int i = tid; i < NSLOT * 4; i += NT) sc->w4[i] = 0.f;
        if (tid < NSLOT) sc->ww[tid] = 0.f;
        if (tid < 256) sc->ctrl[tid] = 0.f;
        for (int i = tid; i < 2048; i += NT) sc->u[i] = 0.f;   // r partials = 0
    }
    __syncthreads();

    for (int t = 0; t < TT; ++t) {
        // ---- P0: reduce P56 r-partials (8 waves) -> ctrl ----
        if (tid < 256) {
            float s = sc->u[tid];
#pragma unroll
            for (int w = 1; w < 8; ++w) s += sc->u[w * 256 + tid];
            sc->ctrl[tid] = s;
        }
        __syncthreads();                                   // B0

        // ---- P1: GEMV1 r-part only (x-part precomputed into xp); f32 weights ----
        {
            const float xpv = xp[(size_t)(b * TT + t) * CDIM + col];   // issued early

            float creg[4];
            creg[0] = sc->ctrl[lane];
            creg[1] = sc->ctrl[64 + lane];
            creg[2] = sc->ctrl[128 + lane];
            creg[3] = sc->ctrl[192 + lane];

            const float4* wqa = (const float4*)wct + col * 2;
            float accs[4] = {0.f, 0.f, 0.f, 0.f};
            if (halfw == 0) {
#pragma unroll
                for (int cc = 0; cc < 16; ++cc) P1_CHUNK(cc);
            } else {
#pragma unroll
                for (int cc = 0; cc < 16; ++cc) P1_CHUNK(16 + cc);
            }
            float s = (accs[0] + accs[1]) + (accs[2] + accs[3]);
            if (halfw == 1) sc->u[col] = s;           // partial to scratch
            __syncthreads();                               // B1
            if (halfw == 0) {
                float z = xpv + s + sc->u[col];
                z = fminf(fmaxf(z, -15.f), 15.f);
                float ex = __expf(2.f * z);
                float hv = (ex - 1.f) / (ex + 1.f);
                sc->h[col] = hv;
                if (t == TT - 1) out[(size_t)b * CDIM + col] = hv;
            }
        }
        if (t == TT - 1) break;
        __syncthreads();                                   // B2

        // ---- P2: GEMV2, f32 weights + regs + readlane; scatter k/e/a ----
        {
            float hreg[4];                                 // loaded by ALL threads (full-wave defined)
#pragma unroll
            for (int j = 0; j < 4; ++j) hreg[j] = sc->h[64 * j + lane];
            if (tid < IDIM) {
                const float4* wq2a = (const float4*)hkb + tid * 2;
                float accs[4] = {0.f, 0.f, 0.f, 0.f};
#pragma unroll
                for (int c = 0; c < 32; ++c) {
                    const float4 w0 = wq2a[c * 956];
                    const float4 w1 = wq2a[c * 956 + 1];
                    const int k0 = c * 8;
                    float a0 = rlane(hreg[(k0 + 0) >> 6], (k0 + 0) & 63);
                    float a1 = rlane(hreg[(k0 + 1) >> 6], (k0 + 1) & 63);
                    float a2 = rlane(hreg[(k0 + 2) >> 6], (k0 + 2) & 63);
                    float a3 = rlane(hreg[(k0 + 3) >> 6], (k0 + 3) & 63);
                    float a4 = rlane(hreg[(k0 + 4) >> 6], (k0 + 4) & 63);
                    float a5 = rlane(hreg[(k0 + 5) >> 6], (k0 + 5) & 63);
                    float a6 = rlane(hreg[(k0 + 6) >> 6], (k0 + 6) & 63);
                    float a7 = rlane(hreg[(k0 + 7) >> 6], (k0 + 7) & 63);
                    accs[c & 3] += w0.x * a0 + w0.y * a1 + w0.z * a2 + w0.w * a3
                                 + w1.x * a4 + w1.y * a5 + w1.z * a6 + w1.w * a7;
                }
                float acc = hbv + (accs[0] + accs[1]) + (accs[2] + accs[3]);
                sc->instr[tid] = acc;
                if (tid < 350) {
                    int hh = (tid * 937) >> 16;     // tid/70
                    int m = tid - hh * RHL;
                    if (m < MLEN) sc->k[hh * MLEN + m] = acc;
                } else if (tid < 414) {
                    sc->e[tid - 350] = acc;
                } else {
                    sc->a[tid - 414] = acc;
                }
            }
        }
        __syncthreads();                                   // B3

        // ---- P3: sim dots via MFMA (split-precision bf16 hi+lo) + fused row norms ----
        {
            const int q   = lane >> 4;    // k-group 0..3
            const int r15 = lane & 15;    // A row-within-tile / B head col

            bf8 bhi[2], blo[2];
#pragma unroll
            for (int kc = 0; kc < 2; ++kc) {
                float kb[8];
                if (r15 < NHEAD) {
                    const float4* k4 = (const float4*)(sc->k + r15 * MLEN + kc * 32 + q * 8);
                    float4 kv0 = k4[0], kv1 = k4[1];
                    kb[0] = kv0.x; kb[1] = kv0.y; kb[2] = kv0.z; kb[3] = kv0.w;
                    kb[4] = kv1.x; kb[5] = kv1.y; kb[6] = kv1.z; kb[7] = kv1.w;
                } else {
#pragma unroll
                    for (int i = 0; i < 8; ++i) kb[i] = 0.f;
                }
                cvt_hi_lo(kb, &bhi[kc], &blo[kc]);
            }

#pragma unroll
            for (int tt2 = 0; tt2 < 4; ++tt2) {
                const int tbase = wave * 64 + tt2 * 16;
                const int n = tbase + r15;
                const int nx = n & 15;
                const float4* m4 = (const float4*)sc->mem + n * 16;
                f32x4 acc = {0.f, 0.f, 0.f, 0.f};
                float nsq = 0.f;
#pragma unroll
                for (int kc = 0; kc < 2; ++kc) {
                    const int j0 = kc * 8 + q * 2;
                    float4 av0 = m4[j0 ^ nx];
                    float4 av1 = m4[(j0 + 1) ^ nx];
                    float aa[8];
                    aa[0] = av0.x; aa[1] = av0.y; aa[2] = av0.z; aa[3] = av0.w;
                    aa[4] = av1.x; aa[5] = av1.y; aa[6] = av1.z; aa[7] = av1.w;
#pragma unroll
                    for (int i = 0; i < 8; ++i) nsq += aa[i] * aa[i];
                    bf8 ahi, alo;
                    cvt_hi_lo(aa, &ahi, &alo);
                    acc = __builtin_amdgcn_mfma_f32_16x16x32_bf16(ahi, bhi[kc], acc, 0, 0, 0);
                    acc = __builtin_amdgcn_mfma_f32_16x16x32_bf16(ahi, blo[kc], acc, 0, 0, 0);
                    acc = __builtin_amdgcn_mfma_f32_16x16x32_bf16(alo, bhi[kc], acc, 0, 0, 0);
                }
                nsq += __shfl_xor(nsq, 16);
                nsq += __shfl_xor(nsq, 32);
                if (q == 0) sc->mn[n] = sqrtf(nsq);
                if (r15 < NHEAD) {
                    float4 st;
                    st.x = acc[0]; st.y = acc[1]; st.z = acc[2]; st.w = acc[3];
                    *(float4*)&sc->u[r15 * NSLOT + tbase + q * 4] = st;
                }
            }
        }
        __syncthreads();                                   // B4

        // ---- P4: addressing, one wave per head (heads 0-3 packed w4, head 4 ww) ----
        if (wave < NHEAD) {
            const int h = wave;
            const float* ins = sc->instr + h * RHL;
            float kv = ins[lane];
            float sq = kv * kv;
#pragma unroll
            for (int off = 32; off; off >>= 1) sq += __shfl_xor(sq, off);
            float kn = sqrtf(sq);
            float beta = __expf(ins[64]);
            float g = 1.f / (1.f + __expf(-ins[65]));
            float v0 = ins[66], v1 = ins[67], v2 = ins[68];
            float mx3 = fmaxf(v0, fmaxf(v1, v2));
            float e0 = __expf(v0 - mx3), e1 = __expf(v1 - mx3), e2 = __expf(v2 - mx3);
            float inv3 = 1.f / (e0 + e1 + e2);
            float s0 = e0 * inv3, s1 = e1 * inv3, s2 = e2 * inv3;
            float tv = ins[69];
            float tp = fmaxf(tv, 0.f) + log1pf(__expf(-fabsf(tv))) + 1.f;

            float uu[8];
#pragma unroll
            for (int j = 0; j < 8; ++j) {
                int slot = j * 64 + lane;
                float d = sc->u[h * NSLOT + slot];
                uu[j] = beta * d / (kn * sc->mn[slot] + 1e-8f);
            }
            float m = uu[0];
#pragma unroll
            for (int j = 1; j < 8; ++j) m = fmaxf(m, uu[j]);
#pragma unroll
            for (int off = 32; off; off >>= 1) m = fmaxf(m, __shfl_xor(m, off));
            float ev[8]; float Z = 0.f;
#pragma unroll
            for (int j = 0; j < 8; ++j) { ev[j] = __expf(uu[j] - m); Z += ev[j]; }
#pragma unroll
            for (int off = 32; off; off >>= 1) Z += __shfl_xor(Z, off);
            float invZ = 1.f / Z;
            float wg[8];
#pragma unroll
            for (int j = 0; j < 8; ++j) {
                int slot = j * 64 + lane;
                float oldw = (h < 4) ? sc->w4[slot * 4 + h] : sc->ww[slot];
                wg[j] = g * ev[j] * invZ + (1.f - g) * oldw;
            }
            // ring shift: fold the wrap-fix into the shuffled SOURCE value
            int lm = (lane + 63) & 63, lp = (lane + 1) & 63;
            float rm[8], rp[8];
#pragma unroll
            for (int j = 0; j < 8; ++j) {
                float sm = (lane == 63) ? wg[(j + 7) & 7] : wg[j];
                float sp = (lane == 0)  ? wg[(j + 1) & 7] : wg[j];
                rm[j] = __shfl(sm, lm);
                rp[j] = __shfl(sp, lp);
            }
            float wt[8]; float S = 0.f;
#pragma unroll
            for (int j = 0; j < 8; ++j) {
                float wsh = s0 * rp[j] + s1 * wg[j] + s2 * rm[j];
                wt[j] = __builtin_amdgcn_exp2f(tp * __builtin_amdgcn_logf(wsh));
                S += wt[j];
            }
#pragma unroll
            for (int off = 32; off; off >>= 1) S += __shfl_xor(S, off);
            float invS = 1.f / (S + 1e-8f);
#pragma unroll
            for (int j = 0; j < 8; ++j) {
                int slot = j * 64 + lane;
                float wnew = wt[j] * invS;
                if (h < 4) sc->w4[slot * 4 + h] = wnew;
                else       sc->ww[slot] = wnew;
            }
        }
        __syncthreads();                                   // B5

        // ---- P56: erase/add update (unchanged) + MFMA read-accumulate -> wave partials ----
        {
            const int rg = lane >> 4, j = lane & 15, base = wave * 64;
            const float4 ev = ((const float4*)sc->e)[j];
            const float4 av = ((const float4*)sc->a)[j];
            float4* m4 = (float4*)sc->mem;
#pragma unroll
            for (int i = 0; i < 16; ++i) {
                const int n = base + 4 * i + rg;
                const int idx = n * 16 + (j ^ (n & 15));
                float4 mv = m4[idx];
                const float wv = sc->ww[n];
                mv.x = mv.x * (1.f - wv * ev.x) + wv * av.x;
                mv.y = mv.y * (1.f - wv * ev.y) + wv * av.y;
                mv.z = mv.z * (1.f - wv * ev.z) + wv * av.z;
                mv.w = mv.w * (1.f - wv * ev.w) + wv * av.w;
                m4[idx] = mv;
            }
            // MFMA: r_partial[head 0..3][m 0..63] = w4^T (4x64) @ Mem'(64x64), this wave's rows.
            const int q = rg, r15 = j;    // aliases: q=lane>>4, r15=lane&15
            bf8 ahi[2], alo[2];
#pragma unroll
            for (int kc = 0; kc < 2; ++kc) {
                float ab[8];
#pragma unroll
                for (int i = 0; i < 8; ++i) {
                    const int n2 = base + kc * 32 + q * 8 + i;
                    ab[i] = (r15 < 4) ? sc->w4[n2 * 4 + r15] : 0.f;
                }
                cvt_hi_lo(ab, &ahi[kc], &alo[kc]);
            }
#pragma unroll
            for (int tt2 = 0; tt2 < 4; ++tt2) {
                f32x4 acc = {0.f, 0.f, 0.f, 0.f};
#pragma unroll
                for (int kc = 0; kc < 2; ++kc) {
                    float bb[8];
#pragma unroll
                    for (int i = 0; i < 8; ++i) {
                        const int n2 = base + kc * 32 + q * 8 + i;
                        const int cc = tt2 * 16 + r15;
                        bb[i] = sc->mem[n2 * 64 + (((cc >> 2) ^ (n2 & 15)) << 2) + (cc & 3)];
                    }
                    bf8 bhi, blo;
                    cvt_hi_lo(bb, &bhi, &blo);
                    acc = __builtin_amdgcn_mfma_f32_16x16x32_bf16(ahi[kc], bhi, acc, 0, 0, 0);
                    acc = __builtin_amdgcn_mfma_f32_16x16x32_bf16(ahi[kc], blo, acc, 0, 0, 0);
                    acc = __builtin_amdgcn_mfma_f32_16x16x32_bf16(alo[kc], bhi, acc, 0, 0, 0);
                }
                if (q == 0) {                 // C rows 0..3 = heads 0..3 live in q==0 lanes
#pragma unroll
                    for (int reg = 0; reg < 4; ++reg)
                        sc->u[wave * 256 + reg * 64 + tt2 * 16 + r15] = acc[reg];
                }
            }
        }
        __syncthreads();                                   // B6
    }
}

extern "C" void kernel_launch(void* const* d_in, const int* in_sizes, int n_in,
                              void* d_out, int out_size, void* d_ws, size_t ws_size,
                              hipStream_t stream) {
    const float* x  = (const float*)d_in[0];
    const float* Wc = (const float*)d_in[1];
    const float* bc = (const float*)d_in[2];
    const float* Hk = (const float*)d_in[3];
    const float* hb = (const float*)d_in[4];
    float* out = (float*)d_out;

    float* xp  = (float*)d_ws;
    float* wct = (float*)((char*)d_ws + WCT_OFF);
    float* hkb = (float*)((char*)d_ws + HKB_OFF);

    static_assert(sizeof(SMem) <= 163840, "LDS overflow");
    (void)hipFuncSetAttribute((const void*)ntm_kernel,
                              hipFuncAttributeMaxDynamicSharedMemorySize,
                              (int)sizeof(SMem));

    hipLaunchKernelGGL(pack_kernel, dim3(478), dim3(256), 0, stream, Wc, Hk, wct, hkb);
    hipLaunchKernelGGL(xpart_kernel, dim3(BB * TT), dim3(256), 0, stream, x, Wc, bc, xp);
    hipLaunchKernelGGL(ntm_kernel, dim3(BB), dim3(NT), sizeof(SMem), stream,
                       xp, hb, wct, hkb, out);
}